// Round 1
// baseline (521.063 us; speedup 1.0000x reference)
//
#include <hip/hip_runtime.h>

#define N_WIDTH 64
#define N_ORDER 4
#define N_ELEMENTS 250
#define N_NODES 1001                        // N_ELEMENTS*N_ORDER+1
#define N_COLL 200
#define NDIM 2
#define MM 5                                // N_ORDER+1
#define ROW (N_NODES * NDIM)                // 2002 floats per (k) row
#define SAMPLE_SLICE (N_WIDTH * ROW)        // 128128 floats per sample
#define BUF_ELEMS ((long)N_COLL * SAMPLE_SLICE)  // 25,625,600 floats per buffer

// ---------------------------------------------------------------------------
// Fused pass-through copy: input buffers -> output regions, float4 vectorized.
// All three buffers copied by one kernel for a single big BW-bound dispatch.
// ---------------------------------------------------------------------------
__global__ void copy3_kernel(const float4* __restrict__ a, float4* __restrict__ oa,
                             const float4* __restrict__ b, float4* __restrict__ ob,
                             const float4* __restrict__ c, float4* __restrict__ oc,
                             long n4) {
    long i = (long)blockIdx.x * blockDim.x + threadIdx.x;
    long stride = (long)gridDim.x * blockDim.x;
    for (; i < n4; i += stride) {
        oa[i] = a[i];
        ob[i] = b[i];
        oc[i] = c[i];
    }
}

// ---------------------------------------------------------------------------
// Scatter: one thread per (w, d) — 128 threads. Each thread does its writes
// sequentially in the reference's loop order (p outer asc, dq inner 0->1) so
// overlapping-position overwrite semantics match exactly.
// ---------------------------------------------------------------------------
__global__ void scatter_kernel(const float* __restrict__ x,
                               const int* __restrict__ flagp,
                               const int* __restrict__ samplep,
                               float* __restrict__ phi_out,
                               float* __restrict__ dphi_out,
                               float* __restrict__ ddphi_out) {
    if (*flagp != 0) return;
    int t = threadIdx.x;
    if (t >= N_WIDTH * NDIM) return;
    int w = t >> 1;
    int d = t & 1;
    int sample = *samplep;

    // x_shift, element index, left node per input dimension
    float xs[NDIM];
    int nl[NDIM];
    for (int q = 0; q < NDIM; ++q) {
        xs[q] = (float)(N_NODES - 1) * x[q];           // X_MIN=0, X_MAX=1
        float id_el = floorf(xs[q] / (float)N_ORDER);
        id_el = fminf(fmaxf(id_el, 0.0f), (float)(N_ELEMENTS - 1));
        nl[q] = (int)(id_el * (float)N_ORDER);
    }
    float xt = (xs[d] - ((float)nl[d] + 2.0f)) * 0.5f; // (xs - 0.5*(nl+nr)) / 2

    // Lagrange bases on nodes {-1,-0.5,0,0.5,1}
    const float nodes[MM] = {-1.0f, -0.5f, 0.0f, 0.5f, 1.0f};
    float inv[MM][MM], r[MM][MM];
    for (int i = 0; i < MM; ++i)
        for (int k = 0; k < MM; ++k) {
            inv[i][k] = (i == k) ? 0.0f : 1.0f / (nodes[i] - nodes[k]);
            r[i][k] = (xt - nodes[k]) * inv[i][k];
        }

    float L[MM], dL[MM], ddL[MM];
    for (int i = 0; i < MM; ++i) {
        float prod = 1.0f;
        for (int k = 0; k < MM; ++k) if (k != i) prod *= r[i][k];
        L[i] = prod;

        float s = 0.0f;
        for (int j = 0; j < MM; ++j) if (j != i) {
            float pr = 1.0f;
            for (int k = 0; k < MM; ++k) if (k != i && k != j) pr *= r[i][k];
            s += inv[i][j] * pr;
        }
        // reference quirk: dL kept only at i == M-1
        dL[i] = (i == MM - 1) ? s : 0.0f;

        float ss = 0.0f;
        for (int j = 0; j < MM; ++j) if (j != i) {
            float s2 = 0.0f;
            for (int k = 0; k < MM; ++k) if (k != i && k != j) {
                float pr = 1.0f;
                for (int l = 0; l < MM; ++l) if (l != i && l != j && l != k) pr *= r[i][l];
                s2 += inv[i][k] * pr;
            }
            ss += inv[i][j] * s2;
        }
        ddL[i] = ss;
    }

    const float dx = 0.5f * (float)N_ORDER * 1.0f / (float)(N_NODES - 1);  // 0.002
    const float inv_dx = 1.0f / dx;
    const float inv_dx2 = inv_dx * inv_dx;

    long base = (long)sample * SAMPLE_SLICE + (long)w * ROW;  // + pos*2 + d
    for (int p = 0; p < MM; ++p) {
        float v = L[p];
        float dv = dL[p] * inv_dx;
        float ddv = ddL[p] * inv_dx2;
        // dq = 0 then dq = 1 (reference inner loop order)
        long o0 = base + (long)(nl[0] + p) * NDIM + d;
        long o1 = base + (long)(nl[1] + p) * NDIM + d;
        phi_out[o0] = v;   phi_out[o1] = v;
        dphi_out[o0] = dv; dphi_out[o1] = dv;
        ddphi_out[o0] = ddv; ddphi_out[o1] = ddv;
    }
}

// ---------------------------------------------------------------------------
// Reduction: t/dt/ddt[k] = sum_{p,j} weight[k,p,j] * buf[sample,k,p,j]
// One block per k (64 blocks x 256 threads). Reads the already-scattered
// output regions so results match the post-scatter buffers.
// ---------------------------------------------------------------------------
__device__ __forceinline__ float wave_reduce(float v) {
    for (int off = 32; off > 0; off >>= 1) v += __shfl_down(v, off, 64);
    return v;
}

__global__ void reduce_kernel(const float* __restrict__ weight,
                              const float* __restrict__ phi,
                              const float* __restrict__ dphi,
                              const float* __restrict__ ddphi,
                              const int* __restrict__ samplep,
                              float* __restrict__ out) {
    int k = blockIdx.x;
    int tid = threadIdx.x;
    long wbase = (long)k * ROW;
    long pbase = (long)(*samplep) * SAMPLE_SLICE + (long)k * ROW;

    float st = 0.0f, sdt = 0.0f, sddt = 0.0f;
    for (int i = tid; i < ROW; i += blockDim.x) {
        float wv = weight[wbase + i];
        st   += wv * phi[pbase + i];
        sdt  += wv * dphi[pbase + i];
        sddt += wv * ddphi[pbase + i];
    }

    st = wave_reduce(st);
    sdt = wave_reduce(sdt);
    sddt = wave_reduce(sddt);

    __shared__ float sh[3][4];
    int lane = tid & 63;
    int wid = tid >> 6;
    if (lane == 0) { sh[0][wid] = st; sh[1][wid] = sdt; sh[2][wid] = sddt; }
    __syncthreads();
    if (tid == 0) {
        out[k]       = sh[0][0] + sh[0][1] + sh[0][2] + sh[0][3];
        out[64 + k]  = sh[1][0] + sh[1][1] + sh[1][2] + sh[1][3];
        out[128 + k] = sh[2][0] + sh[2][1] + sh[2][2] + sh[2][3];
    }
}

extern "C" void kernel_launch(void* const* d_in, const int* in_sizes, int n_in,
                              void* d_out, int out_size, void* d_ws, size_t ws_size,
                              hipStream_t stream) {
    const float* x       = (const float*)d_in[0];
    const int*   flagp   = (const int*)d_in[1];
    const int*   samplep = (const int*)d_in[2];
    const float* weight  = (const float*)d_in[3];
    const float* phi_in  = (const float*)d_in[4];
    const float* dphi_in = (const float*)d_in[5];
    const float* ddphi_in= (const float*)d_in[6];

    float* out = (float*)d_out;
    float* t_out      = out;            // 192 floats: t(64), dt(64), ddt(64)
    float* phi_out    = out + 192;
    float* dphi_out   = phi_out + BUF_ELEMS;
    float* ddphi_out  = dphi_out + BUF_ELEMS;

    long n4 = BUF_ELEMS / 4;            // 6,406,400 float4 per buffer

    copy3_kernel<<<2048, 256, 0, stream>>>(
        (const float4*)phi_in,  (float4*)phi_out,
        (const float4*)dphi_in, (float4*)dphi_out,
        (const float4*)ddphi_in,(float4*)ddphi_out, n4);

    scatter_kernel<<<1, 128, 0, stream>>>(x, flagp, samplep,
                                          phi_out, dphi_out, ddphi_out);

    reduce_kernel<<<64, 256, 0, stream>>>(weight, phi_out, dphi_out, ddphi_out,
                                          samplep, t_out);
}